// Round 10
// baseline (306.388 us; speedup 1.0000x reference)
//
#include <hip/hip_runtime.h>

#define B_   4
#define L_   1024
#define D_   16
#define H_   32
#define TAU_ 64
#define EMB_ 8
#define AEP_ 34   // ae_lds stride: even -> 8B-aligned float2 reads, 2-way banks (free)
#define TI_  32   // i-tile height: 2048 blocks = 8 blocks/CU -> 100% occupancy

typedef float f2 __attribute__((ext_vector_type(2)));

// ---------------------------------------------------------------------------
// Kernel 1: precompute (R9 verbatim)
// ---------------------------------------------------------------------------
__global__ __launch_bounds__(256) void precompute_kernel(
    const float* __restrict__ x, const float* __restrict__ dtt,
    const float* __restrict__ W1, const float* __restrict__ b1,
    float* __restrict__ ai, float* __restrict__ aj, float* __restrict__ ae)
{
    const int id = blockIdx.x * 256 + threadIdx.x;
    const int NA = B_ * L_ * H_;
    if (id < NA) {
        const int h   = id & (H_ - 1);
        const int row = id >> 5;                 // b*L + l
        const float4* xr4 = (const float4*)(x + row * D_);
        const float4 v0 = xr4[0], v1 = xr4[1], v2 = xr4[2], v3 = xr4[3];
        const float xv[D_] = {v0.x, v0.y, v0.z, v0.w, v1.x, v1.y, v1.z, v1.w,
                              v2.x, v2.y, v2.z, v2.w, v3.x, v3.y, v3.z, v3.w};
        float s1 = 0.f, s2 = 0.f;
#pragma unroll
        for (int d = 0; d < D_; ++d) {
            s1 = fmaf(xv[d], W1[d * H_ + h], s1);
            s2 = fmaf(xv[d], W1[(D_ + d) * H_ + h], s2);
        }
        ai[id] = s1;
        aj[id] = s2;
    } else {
        const int k = id - NA;
        if (k < (TAU_ + 1) * H_) {
            const int h = k & (H_ - 1);
            const int t = k >> 5;
            float s = b1[h];
#pragma unroll
            for (int e = 0; e < EMB_; ++e)
                s = fmaf(dtt[t * EMB_ + e], W1[(2 * D_ + e) * H_ + h], s);
            ae[k] = s;
        }
    }
}

// ---------------------------------------------------------------------------
// Kernel 2: bias kernel (R9 verbatim). Idempotent: pure function of ws
// arrays + inputs; launched 17x for the slope measurement.
// ---------------------------------------------------------------------------
__global__ __launch_bounds__(256, 8) void bias_kernel(
    const float* __restrict__ ai, const float* __restrict__ aj,
    const float* __restrict__ ae, const float* __restrict__ W2,
    const float* __restrict__ b2p, float* __restrict__ out)
{
    __shared__ float ae_lds[(TAU_ + 1) * AEP_];

    const int b    = blockIdx.z;
    const int i0   = blockIdx.y * TI_;
    const int j0   = blockIdx.x * 64;
    const int tid  = threadIdx.x;
    const int lane = tid & 63;
    const int w    = __builtin_amdgcn_readfirstlane(tid >> 6);
    const int j    = j0 + lane;

    const bool c0  = (j0 >= i0 + TI_);     // dt==0 over whole tile
    const bool c64 = (i0 >= j0 + 128);     // dt==64 over whole tile
    const bool constpath = c0 || c64;

    const float b2 = *b2p;

    f2 r2[H_ / 2];
    {
        const float* ajr = aj + ((size_t)(b * L_ + j)) * H_;
#pragma unroll
        for (int h = 0; h < H_; h += 4) {
            const float4 v = *(const float4*)(ajr + h);
            r2[(h >> 1) + 0] = (f2){v.x, v.y};
            r2[(h >> 1) + 1] = (f2){v.z, v.w};
        }
    }

    if (constpath) {
        const float* aec = ae + (c0 ? 0 : TAU_) * H_;   // uniform -> s_load
#pragma unroll
        for (int h = 0; h < H_; h += 2) {
            const f2 e = {aec[h], aec[h + 1]};
            r2[h >> 1] += e;
        }
    } else {
        for (int k = tid; k < (TAU_ + 1) * H_; k += 256)
            ae_lds[(k >> 5) * AEP_ + (k & 31)] = ae[k];
        __syncthreads();
    }

    const float* aiBase = ai + ((size_t)(b * L_ + i0 + w * 8)) * H_;
    float* outb = out + ((size_t)b) * L_ * L_ + ((size_t)(i0 + w * 8)) * L_ + j;
    const f2 z2 = {0.f, 0.f};

    if (constpath) {
        const float pc = b2 - 0.2f * (c0 ? 0.f : (float)TAU_);
        for (int ii = 0; ii < 8; ii += 2) {
            const float* ar0 = aiBase + (ii + 0) * H_;   // uniform -> s_load
            const float* ar1 = aiBase + (ii + 1) * H_;
            f2 acc0 = z2, acc1 = z2;
#pragma unroll
            for (int h = 0; h < H_; h += 2) {
                const f2 wv = {W2[h], W2[h + 1]};
                const f2 a0 = {ar0[h], ar0[h + 1]};
                const f2 a1 = {ar1[h], ar1[h + 1]};
                f2 p0 = a0 + r2[h >> 1];
                f2 p1 = a1 + r2[h >> 1];
                p0 = __builtin_elementwise_max(p0, z2);
                p1 = __builtin_elementwise_max(p1, z2);
                acc0 = __builtin_elementwise_fma(p0, wv, acc0);
                acc1 = __builtin_elementwise_fma(p1, wv, acc1);
            }
            __builtin_nontemporal_store(acc0.x + acc0.y + pc, outb + (size_t)(ii + 0) * L_);
            __builtin_nontemporal_store(acc1.x + acc1.y + pc, outb + (size_t)(ii + 1) * L_);
        }
    } else {
        for (int ii = 0; ii < 8; ++ii) {
            const int i   = i0 + w * 8 + ii;
            const int d   = i - j;
            const int dt  = d < 0 ? 0 : (d > TAU_ ? TAU_ : d);
            const f2* eL  = (const f2*)&ae_lds[dt * AEP_];
            const float* ar = aiBase + ii * H_;
            f2 acc = z2;
#pragma unroll
            for (int h = 0; h < H_; h += 2) {
                const f2 wv = {W2[h], W2[h + 1]};
                const f2 a  = {ar[h], ar[h + 1]};
                f2 p = a + r2[h >> 1];
                p = p + eL[h >> 1];
                p = __builtin_elementwise_max(p, z2);
                acc = __builtin_elementwise_fma(p, wv, acc);
            }
            __builtin_nontemporal_store(acc.x + acc.y + b2 - 0.2f * (float)dt,
                                        outb + (size_t)ii * L_);
        }
    }
}

extern "C" void kernel_launch(void* const* d_in, const int* in_sizes, int n_in,
                              void* d_out, int out_size, void* d_ws, size_t ws_size,
                              hipStream_t stream) {
    const float* x   = (const float*)d_in[0];
    const float* dtt = (const float*)d_in[1];
    const float* W1  = (const float*)d_in[2];
    const float* b1  = (const float*)d_in[3];
    const float* W2  = (const float*)d_in[4];
    const float* b2  = (const float*)d_in[5];
    float* out = (float*)d_out;

    float* ws = (float*)d_ws;
    float* ai = ws;                          // B*L*H floats
    float* aj = ws + B_ * L_ * H_;           // B*L*H floats
    float* ae = ws + 2 * B_ * L_ * H_;       // 65*H floats

    const int total  = B_ * L_ * H_ + (TAU_ + 1) * H_;
    const int blocks = (total + 255) / 256;
    hipLaunchKernelGGL(precompute_kernel, dim3(blocks), dim3(256), 0, stream,
                       x, dtt, W1, b1, ai, aj, ae);

    // SLOPE MEASUREMENT: 17 identical idempotent bias launches.
    // dur = (P + OH) + 17*B_eff; with R9's 28.07 = (P + OH) + B_eff:
    //   B_eff = (dur - 28.07) / 16.
    dim3 grid(L_ / 64, L_ / TI_, B_);
    for (int rep = 0; rep < 17; ++rep) {
        hipLaunchKernelGGL(bias_kernel, grid, dim3(256), 0, stream,
                           ai, aj, ae, W2, b2, out);
    }
}

// Round 12
// 86.072 us; speedup vs baseline: 3.5597x; 3.5597x over previous
//
#include <hip/hip_runtime.h>

#define B_   4
#define L_   1024
#define D_   16
#define H_   32
#define TAU_ 64
#define EMB_ 8
#define AEP_ 34   // ae_lds stride: even -> 8B-aligned f2 reads, 2-way banks (free)
#define TI_  16   // i-tile height (4 rows/wave)
#define JT_  128  // j-tile width (2 cols/lane) -> 8*64*4 = 2048 blocks = 100% occ

typedef float f2 __attribute__((ext_vector_type(2)));

// ---------------------------------------------------------------------------
// Kernel 1: precompute (R9 verbatim)
//   ai[b,l,h] = x[b,l,:] @ W1[0:16, h]
//   aj[b,l,h] = x[b,l,:] @ W1[16:32, h]
//   ae[t,h]   = dt_table[t,:] @ W1[32:40, h] + b1[h]
// ---------------------------------------------------------------------------
__global__ __launch_bounds__(256) void precompute_kernel(
    const float* __restrict__ x, const float* __restrict__ dtt,
    const float* __restrict__ W1, const float* __restrict__ b1,
    float* __restrict__ ai, float* __restrict__ aj, float* __restrict__ ae)
{
    const int id = blockIdx.x * 256 + threadIdx.x;
    const int NA = B_ * L_ * H_;
    if (id < NA) {
        const int h   = id & (H_ - 1);
        const int row = id >> 5;                 // b*L + l
        const float4* xr4 = (const float4*)(x + row * D_);
        const float4 v0 = xr4[0], v1 = xr4[1], v2 = xr4[2], v3 = xr4[3];
        const float xv[D_] = {v0.x, v0.y, v0.z, v0.w, v1.x, v1.y, v1.z, v1.w,
                              v2.x, v2.y, v2.z, v2.w, v3.x, v3.y, v3.z, v3.w};
        float s1 = 0.f, s2 = 0.f;
#pragma unroll
        for (int d = 0; d < D_; ++d) {
            s1 = fmaf(xv[d], W1[d * H_ + h], s1);
            s2 = fmaf(xv[d], W1[(D_ + d) * H_ + h], s2);
        }
        ai[id] = s1;
        aj[id] = s2;
    } else {
        const int k = id - NA;
        if (k < (TAU_ + 1) * H_) {
            const int h = k & (H_ - 1);
            const int t = k >> 5;
            float s = b1[h];
#pragma unroll
            for (int e = 0; e < EMB_; ++e)
                s = fmaf(dtt[t * EMB_ + e], W1[(2 * D_ + e) * H_ + h], s);
            ae[k] = s;
        }
    }
}

// ---------------------------------------------------------------------------
// Kernel 2: bias kernel, 2-j-per-lane edition.
// R10 slope measurement: bias = 17.4 us, latency-bound on wave-uniform ai row
// s_loads (SMEM is out-of-order -> lgkmcnt(0) full drain per row, no
// pipelining). Fix: amortize -- each lane owns 2 adjacent j columns, so each
// row s_load stall covers 2x the VALU work. Tile 16i x 128j keeps grid at
// 2048 blocks = 8 blocks/CU = 100% occupancy. NT f2 stores (512 B/wave).
// ---------------------------------------------------------------------------
__global__ __launch_bounds__(256, 8) void bias_kernel(
    const float* __restrict__ ai, const float* __restrict__ aj,
    const float* __restrict__ ae, const float* __restrict__ W2,
    const float* __restrict__ b2p, float* __restrict__ out)
{
    __shared__ float ae_lds[(TAU_ + 1) * AEP_];

    const int b    = blockIdx.z;
    const int i0   = blockIdx.y * TI_;
    const int j0   = blockIdx.x * JT_;
    const int tid  = threadIdx.x;
    const int lane = tid & 63;
    const int w    = __builtin_amdgcn_readfirstlane(tid >> 6);
    const int jp   = j0 + lane * 2;

    // i in [i0, i0+15], j in [j0, j0+127].
    const bool c0  = (j0 >= i0 + TI_);            // max(i)-min(j) <= 0
    const bool c64 = (i0 >= j0 + JT_ + TAU_ - 1); // min(i)-max(j) >= 64
    const bool constpath = c0 || c64;

    const float b2 = *b2p;

    // Per-lane column vectors for the two owned j's.
    f2 r2a[H_ / 2], r2b[H_ / 2];
    {
        const float* ajr = aj + ((size_t)(b * L_ + jp)) * H_;
#pragma unroll
        for (int h = 0; h < H_; h += 4) {
            const float4 va = *(const float4*)(ajr + h);
            const float4 vb = *(const float4*)(ajr + H_ + h);
            r2a[(h >> 1) + 0] = (f2){va.x, va.y};
            r2a[(h >> 1) + 1] = (f2){va.z, va.w};
            r2b[(h >> 1) + 0] = (f2){vb.x, vb.y};
            r2b[(h >> 1) + 1] = (f2){vb.z, vb.w};
        }
    }

    if (constpath) {
        const float* aec = ae + (c0 ? 0 : TAU_) * H_;   // uniform -> s_load
#pragma unroll
        for (int h = 0; h < H_; h += 2) {
            const f2 e = {aec[h], aec[h + 1]};
            r2a[h >> 1] += e;
            r2b[h >> 1] += e;
        }
    } else {
        for (int k = tid; k < (TAU_ + 1) * H_; k += 256)
            ae_lds[(k >> 5) * AEP_ + (k & 31)] = ae[k];
        __syncthreads();   // block-uniform branch
    }

    const float* aiBase = ai + ((size_t)(b * L_ + i0 + w * 4)) * H_;
    float* outb = out + ((size_t)b) * L_ * L_ + ((size_t)(i0 + w * 4)) * L_ + jp;
    const f2 z2 = {0.f, 0.f};

    if (constpath) {
        const float pc = b2 - 0.2f * (c0 ? 0.f : (float)TAU_);
#pragma unroll
        for (int ii = 0; ii < 4; ++ii) {
            const float* ar = aiBase + ii * H_;          // uniform -> s_load
            f2 acc0 = z2, acc1 = z2;
#pragma unroll
            for (int h = 0; h < H_; h += 2) {
                const f2 wv = {W2[h], W2[h + 1]};        // sgpr pair
                const f2 a  = {ar[h], ar[h + 1]};        // sgpr pair
                f2 p0 = a + r2a[h >> 1];                 // v_pk_add_f32
                f2 p1 = a + r2b[h >> 1];
                p0 = __builtin_elementwise_max(p0, z2);  // v_pk_max_f32
                p1 = __builtin_elementwise_max(p1, z2);
                acc0 = __builtin_elementwise_fma(p0, wv, acc0);  // v_pk_fma_f32
                acc1 = __builtin_elementwise_fma(p1, wv, acc1);
            }
            const f2 o = {acc0.x + acc0.y + pc, acc1.x + acc1.y + pc};
            __builtin_nontemporal_store(o, (f2*)(outb + (size_t)ii * L_));
        }
    } else {
#pragma unroll
        for (int ii = 0; ii < 4; ++ii) {
            const int i   = i0 + w * 4 + ii;
            const int d0  = i - jp;
            const int d1  = d0 - 1;
            const int dt0 = d0 < 0 ? 0 : (d0 > TAU_ ? TAU_ : d0);
            const int dt1 = d1 < 0 ? 0 : (d1 > TAU_ ? TAU_ : d1);
            const f2* e0  = (const f2*)&ae_lds[dt0 * AEP_];  // 8B aligned
            const f2* e1  = (const f2*)&ae_lds[dt1 * AEP_];
            const float* ar = aiBase + ii * H_;
            f2 acc0 = z2, acc1 = z2;
#pragma unroll
            for (int h = 0; h < H_; h += 2) {
                const f2 wv = {W2[h], W2[h + 1]};
                const f2 a  = {ar[h], ar[h + 1]};
                f2 p0 = a + r2a[h >> 1] + e0[h >> 1];
                f2 p1 = a + r2b[h >> 1] + e1[h >> 1];
                p0 = __builtin_elementwise_max(p0, z2);
                p1 = __builtin_elementwise_max(p1, z2);
                acc0 = __builtin_elementwise_fma(p0, wv, acc0);
                acc1 = __builtin_elementwise_fma(p1, wv, acc1);
            }
            const f2 o = {acc0.x + acc0.y + b2 - 0.2f * (float)dt0,
                          acc1.x + acc1.y + b2 - 0.2f * (float)dt1};
            __builtin_nontemporal_store(o, (f2*)(outb + (size_t)ii * L_));
        }
    }
}

extern "C" void kernel_launch(void* const* d_in, const int* in_sizes, int n_in,
                              void* d_out, int out_size, void* d_ws, size_t ws_size,
                              hipStream_t stream) {
    const float* x   = (const float*)d_in[0];
    const float* dtt = (const float*)d_in[1];
    const float* W1  = (const float*)d_in[2];
    const float* b1  = (const float*)d_in[3];
    const float* W2  = (const float*)d_in[4];
    const float* b2  = (const float*)d_in[5];
    float* out = (float*)d_out;

    float* ws = (float*)d_ws;
    float* ai = ws;                          // B*L*H floats
    float* aj = ws + B_ * L_ * H_;           // B*L*H floats
    float* ae = ws + 2 * B_ * L_ * H_;       // 65*H floats

    const int total  = B_ * L_ * H_ + (TAU_ + 1) * H_;
    const int blocks = (total + 255) / 256;
    hipLaunchKernelGGL(precompute_kernel, dim3(blocks), dim3(256), 0, stream,
                       x, dtt, W1, b1, ai, aj, ae);

    dim3 grid(L_ / JT_, L_ / TI_, B_);
    hipLaunchKernelGGL(bias_kernel, grid, dim3(256), 0, stream,
                       ai, aj, ae, W2, b2, out);
}

// Round 13
// 27.444 us; speedup vs baseline: 11.1641x; 3.1363x over previous
//
#include <hip/hip_runtime.h>

#define B_   4
#define L_   1024
#define D_   16
#define H_   32
#define TAU_ 64
#define EMB_ 8
#define AEP_ 34   // ae_lds stride: even -> 8B-aligned f2 reads, 2-way banks (free)
#define TI_  32   // i-tile height: 2048 blocks = 8 blocks/CU -> 100% occupancy

typedef float f2 __attribute__((ext_vector_type(2)));

// ---------------------------------------------------------------------------
// Kernel 1: precompute (R9 verbatim)
//   ai[b,l,h] = x[b,l,:] @ W1[0:16, h]
//   aj[b,l,h] = x[b,l,:] @ W1[16:32, h]
//   ae[t,h]   = dt_table[t,:] @ W1[32:40, h] + b1[h]
// ---------------------------------------------------------------------------
__global__ __launch_bounds__(256) void precompute_kernel(
    const float* __restrict__ x, const float* __restrict__ dtt,
    const float* __restrict__ W1, const float* __restrict__ b1,
    float* __restrict__ ai, float* __restrict__ aj, float* __restrict__ ae)
{
    const int id = blockIdx.x * 256 + threadIdx.x;
    const int NA = B_ * L_ * H_;
    if (id < NA) {
        const int h   = id & (H_ - 1);
        const int row = id >> 5;                 // b*L + l
        const float4* xr4 = (const float4*)(x + row * D_);
        const float4 v0 = xr4[0], v1 = xr4[1], v2 = xr4[2], v3 = xr4[3];
        const float xv[D_] = {v0.x, v0.y, v0.z, v0.w, v1.x, v1.y, v1.z, v1.w,
                              v2.x, v2.y, v2.z, v2.w, v3.x, v3.y, v3.z, v3.w};
        float s1 = 0.f, s2 = 0.f;
#pragma unroll
        for (int d = 0; d < D_; ++d) {
            s1 = fmaf(xv[d], W1[d * H_ + h], s1);
            s2 = fmaf(xv[d], W1[(D_ + d) * H_ + h], s2);
        }
        ai[id] = s1;
        aj[id] = s2;
    } else {
        const int k = id - NA;
        if (k < (TAU_ + 1) * H_) {
            const int h = k & (H_ - 1);
            const int t = k >> 5;
            float s = b1[h];
#pragma unroll
            for (int e = 0; e < EMB_; ++e)
                s = fmaf(dtt[t * EMB_ + e], W1[(2 * D_ + e) * H_ + h], s);
            ae[k] = s;
        }
    }
}

// ---------------------------------------------------------------------------
// Kernel 2: bias kernel, LDS-broadcast edition (R9 + one change).
// R10 slope measurement: bias = 17.4 us, serialized on per-row SMEM s_loads
// (scalar path forces lgkmcnt drain per row; cannot pipeline). R12 showed
// per-lane restructuring explodes FETCH. Single-variable fix here: stage the
// 32-row ai tile in LDS once (4 KB, 1 float4/thread, coalesced), then read
// rows as wave-uniform-address ds_read_b128 broadcasts -- conflict-free,
// pipelined via fine-grained lgkmcnt(N). Everything else R9-identical:
// tile 32x64, 2048 blocks (100% occ), pk-f32 math, NT dword stores.
// ---------------------------------------------------------------------------
__global__ __launch_bounds__(256, 8) void bias_kernel(
    const float* __restrict__ ai, const float* __restrict__ aj,
    const float* __restrict__ ae, const float* __restrict__ W2,
    const float* __restrict__ b2p, float* __restrict__ out)
{
    __shared__ float ai_lds[TI_ * H_];            // 4 KB: this block's ai tile
    __shared__ float ae_lds[(TAU_ + 1) * AEP_];   // 8.8 KB: band blocks only

    const int b    = blockIdx.z;
    const int i0   = blockIdx.y * TI_;
    const int j0   = blockIdx.x * 64;
    const int tid  = threadIdx.x;
    const int lane = tid & 63;
    const int w    = __builtin_amdgcn_readfirstlane(tid >> 6);
    const int j    = j0 + lane;

    const bool c0  = (j0 >= i0 + TI_);     // dt==0 over whole tile
    const bool c64 = (i0 >= j0 + 128);     // dt==64 over whole tile
    const bool constpath = c0 || c64;

    const float b2 = *b2p;

    // ---- Stage ai tile: 32 rows x 32 h = 1024 floats = 256 float4. ----
    {
        const float4* src = (const float4*)(ai + ((size_t)(b * L_ + i0)) * H_);
        ((float4*)ai_lds)[tid] = src[tid];
    }

    // Per-lane column vector r2[h/2] = aj[j, h..h+1] (+ ae row on const path).
    f2 r2[H_ / 2];
    {
        const float* ajr = aj + ((size_t)(b * L_ + j)) * H_;
#pragma unroll
        for (int h = 0; h < H_; h += 4) {
            const float4 v = *(const float4*)(ajr + h);
            r2[(h >> 1) + 0] = (f2){v.x, v.y};
            r2[(h >> 1) + 1] = (f2){v.z, v.w};
        }
    }

    if (constpath) {
        const float* aec = ae + (c0 ? 0 : TAU_) * H_;   // uniform -> s_load, once
#pragma unroll
        for (int h = 0; h < H_; h += 2) {
            const f2 e = {aec[h], aec[h + 1]};
            r2[h >> 1] += e;
        }
    } else {
        for (int k = tid; k < (TAU_ + 1) * H_; k += 256)
            ae_lds[(k >> 5) * AEP_ + (k & 31)] = ae[k];
    }
    __syncthreads();   // covers ai_lds (all paths) + ae_lds (band)

    const float* aiW = &ai_lds[(w * 8) * H_];   // wave's 8 rows in LDS
    float* outb = out + ((size_t)b) * L_ * L_ + ((size_t)(i0 + w * 8)) * L_ + j;
    const f2 z2 = {0.f, 0.f};

    if (constpath) {
        const float pc = b2 - 0.2f * (c0 ? 0.f : (float)TAU_);
        for (int ii = 0; ii < 8; ii += 2) {
            const float4* ar0 = (const float4*)&aiW[(ii + 0) * H_];  // uniform
            const float4* ar1 = (const float4*)&aiW[(ii + 1) * H_];  // broadcast
            f2 acc0 = z2, acc1 = z2;
#pragma unroll
            for (int q = 0; q < 8; ++q) {
                const float4 q0 = ar0[q];       // ds_read_b128, pipelined
                const float4 q1 = ar1[q];
                const int h = q * 4;
                const f2 wv0 = {W2[h], W2[h + 1]};
                const f2 wv1 = {W2[h + 2], W2[h + 3]};
                f2 p00 = (f2){q0.x, q0.y} + r2[(h >> 1) + 0];
                f2 p01 = (f2){q0.z, q0.w} + r2[(h >> 1) + 1];
                f2 p10 = (f2){q1.x, q1.y} + r2[(h >> 1) + 0];
                f2 p11 = (f2){q1.z, q1.w} + r2[(h >> 1) + 1];
                p00 = __builtin_elementwise_max(p00, z2);
                p01 = __builtin_elementwise_max(p01, z2);
                p10 = __builtin_elementwise_max(p10, z2);
                p11 = __builtin_elementwise_max(p11, z2);
                acc0 = __builtin_elementwise_fma(p00, wv0, acc0);
                acc0 = __builtin_elementwise_fma(p01, wv1, acc0);
                acc1 = __builtin_elementwise_fma(p10, wv0, acc1);
                acc1 = __builtin_elementwise_fma(p11, wv1, acc1);
            }
            __builtin_nontemporal_store(acc0.x + acc0.y + pc, outb + (size_t)(ii + 0) * L_);
            __builtin_nontemporal_store(acc1.x + acc1.y + pc, outb + (size_t)(ii + 1) * L_);
        }
    } else {
        for (int ii = 0; ii < 8; ++ii) {
            const int i   = i0 + w * 8 + ii;
            const int d   = i - j;
            const int dt  = d < 0 ? 0 : (d > TAU_ ? TAU_ : d);
            const f2* eL  = (const f2*)&ae_lds[dt * AEP_];   // 8B aligned
            const float4* ar = (const float4*)&aiW[ii * H_];
            f2 acc = z2;
#pragma unroll
            for (int q = 0; q < 8; ++q) {
                const float4 qa = ar[q];
                const int h = q * 4;
                const f2 wv0 = {W2[h], W2[h + 1]};
                const f2 wv1 = {W2[h + 2], W2[h + 3]};
                f2 p0 = (f2){qa.x, qa.y} + r2[(h >> 1) + 0] + eL[(h >> 1) + 0];
                f2 p1 = (f2){qa.z, qa.w} + r2[(h >> 1) + 1] + eL[(h >> 1) + 1];
                p0 = __builtin_elementwise_max(p0, z2);
                p1 = __builtin_elementwise_max(p1, z2);
                acc = __builtin_elementwise_fma(p0, wv0, acc);
                acc = __builtin_elementwise_fma(p1, wv1, acc);
            }
            __builtin_nontemporal_store(acc.x + acc.y + b2 - 0.2f * (float)dt,
                                        outb + (size_t)ii * L_);
        }
    }
}

extern "C" void kernel_launch(void* const* d_in, const int* in_sizes, int n_in,
                              void* d_out, int out_size, void* d_ws, size_t ws_size,
                              hipStream_t stream) {
    const float* x   = (const float*)d_in[0];
    const float* dtt = (const float*)d_in[1];
    const float* W1  = (const float*)d_in[2];
    const float* b1  = (const float*)d_in[3];
    const float* W2  = (const float*)d_in[4];
    const float* b2  = (const float*)d_in[5];
    float* out = (float*)d_out;

    float* ws = (float*)d_ws;
    float* ai = ws;                          // B*L*H floats
    float* aj = ws + B_ * L_ * H_;           // B*L*H floats
    float* ae = ws + 2 * B_ * L_ * H_;       // 65*H floats

    const int total  = B_ * L_ * H_ + (TAU_ + 1) * H_;
    const int blocks = (total + 255) / 256;
    hipLaunchKernelGGL(precompute_kernel, dim3(blocks), dim3(256), 0, stream,
                       x, dtt, W1, b1, ai, aj, ae);

    dim3 grid(L_ / 64, L_ / TI_, B_);
    hipLaunchKernelGGL(bias_kernel, grid, dim3(256), 0, stream,
                       ai, aj, ae, W2, b2, out);
}